// Round 15
// baseline (255.880 us; speedup 1.0000x reference)
//
#include <hip/hip_runtime.h>
#include <math.h>

#define IN_CH 128
#define HID 64
#define OUT_CH 10

typedef unsigned int uint32;
typedef unsigned char u8;
typedef unsigned short bf16u;
typedef __attribute__((ext_vector_type(8))) short bf16x8;
typedef __attribute__((ext_vector_type(4))) float f32x4;
typedef __attribute__((ext_vector_type(2))) float f32x2;

static __device__ inline bf16u f2bf(float f) {
    uint32 u = __float_as_uint(f);
    u += 0x7fff + ((u >> 16) & 1);          // round-nearest-even
    return (bf16u)(u >> 16);
}
static __device__ inline uint32 pack2(float a, float b) {
    return (uint32)f2bf(a) | ((uint32)f2bf(b) << 16);
}
static __device__ inline u8 f2fp8(float v) {
    uint32 p = __builtin_amdgcn_cvt_pk_fp8_f32(v, v, 0, false);
    return (u8)(p & 0xff);
}
static __device__ inline void acc_fp8x4(uint32 u, float& a0, float& a1,
                                        float& a2, float& a3) {
    f32x2 lo = __builtin_amdgcn_cvt_pk_f32_fp8((int)u, false);
    f32x2 hi = __builtin_amdgcn_cvt_pk_f32_fp8((int)u, true);
    a0 += lo.x; a1 += lo.y; a2 += hi.x; a3 += hi.y;
}

// neighbor-sum, fp8 y rows (16 dwords). lanes: c2=lane&15 (4 ch), h=lane>>4
static __device__ inline void gather_nbrs8(
    const uint32* __restrict__ y8, const int* __restrict__ col,
    int rs, int re, int h, int c2,
    float& a0, float& a1, float& a2, float& a3)
{
    int j = rs;
    for (; j + 16 <= re; j += 16) {
        int s0 = col[j + h];
        int s1 = col[j + 4 + h];
        int s2 = col[j + 8 + h];
        int s3 = col[j + 12 + h];
        uint32 u0 = y8[(long)s0 * 16 + c2];
        uint32 u1 = y8[(long)s1 * 16 + c2];
        uint32 u2 = y8[(long)s2 * 16 + c2];
        uint32 u3 = y8[(long)s3 * 16 + c2];
        acc_fp8x4(u0, a0, a1, a2, a3);
        acc_fp8x4(u1, a0, a1, a2, a3);
        acc_fp8x4(u2, a0, a1, a2, a3);
        acc_fp8x4(u3, a0, a1, a2, a3);
    }
    for (; j + 4 <= re; j += 4) {
        uint32 u = y8[(long)col[j + h] * 16 + c2];
        acc_fp8x4(u, a0, a1, a2, a3);
    }
    int r = re - j;
    if (h < r) {
        uint32 u = y8[(long)col[j + h] * 16 + c2];
        acc_fp8x4(u, a0, a1, a2, a3);
    }
}

// ---------- CSR build: degree count + per-edge ordinal ----------
__global__ __launch_bounds__(256) void k_count(
    const int* __restrict__ dst, int* __restrict__ cnt,
    int* __restrict__ pos, int E)
{
    int e = blockIdx.x * 256 + threadIdx.x;
    if (e < E) pos[e] = atomicAdd(&cnt[dst[e]], 1);
}

// ---------- scan + place fused (49 co-resident blocks, 2 grid syncs) ----------
// phase 1: cnt -> row_ptr (exclusive scan, partials + spin barrier)
// phase 2: after row_ptr published (agent-scope), place all E edges.
__global__ __launch_bounds__(256) void k_scanplace(
    const int* __restrict__ cnt, int* __restrict__ row_ptr,
    int* __restrict__ partials, int* __restrict__ counter, int* __restrict__ counter2,
    const int* __restrict__ src, const int* __restrict__ dst,
    const int* __restrict__ pos, int* __restrict__ col,
    int N, int E, int nch)
{
    __shared__ int red[256];
    int tid = threadIdx.x;
    int bid = blockIdx.x;
    long base = (long)bid * 1024 + tid * 4;
    int v[4]; int s = 0;
    #pragma unroll
    for (int i = 0; i < 4; i++) {
        long idx = base + i;
        v[i] = (idx < N) ? cnt[idx] : 0;
        s += v[i];
    }
    red[tid] = s;
    __syncthreads();
    for (int off = 1; off < 256; off <<= 1) {
        int t = (tid >= off) ? red[tid - off] : 0;
        __syncthreads();
        red[tid] += t;
        __syncthreads();
    }
    int myexcl = red[tid] - s;
    if (tid == 255) {
        __hip_atomic_store(&partials[bid], red[255], __ATOMIC_RELEASE,
                           __HIP_MEMORY_SCOPE_AGENT);
        atomicAdd(counter, 1);
    }
    if (tid == 0) {
        while (__hip_atomic_load(counter, __ATOMIC_ACQUIRE,
                                 __HIP_MEMORY_SCOPE_AGENT) < nch) { }
    }
    __syncthreads();
    int off = 0;
    for (int i = tid; i < bid; i += 256)
        off += __hip_atomic_load(&partials[i], __ATOMIC_RELAXED,
                                 __HIP_MEMORY_SCOPE_AGENT);
    __syncthreads();
    red[tid] = off;
    __syncthreads();
    for (int o = 128; o; o >>= 1) {
        if (tid < o) red[tid] += red[tid + o];
        __syncthreads();
    }
    int run = red[0] + myexcl;
    #pragma unroll
    for (int i = 0; i < 4; i++) {
        long idx = base + i;
        if (idx < N)
            __hip_atomic_store(&row_ptr[idx], run, __ATOMIC_RELAXED,
                               __HIP_MEMORY_SCOPE_AGENT);
        run += v[i];
    }
    if (bid == 0 && tid == 0)
        __hip_atomic_store(&row_ptr[N], E, __ATOMIC_RELAXED,
                           __HIP_MEMORY_SCOPE_AGENT);
    // ---- barrier 2: wait for all row_ptr slices ----
    __threadfence();
    __syncthreads();
    if (tid == 0) {
        atomicAdd(counter2, 1);
        while (__hip_atomic_load(counter2, __ATOMIC_ACQUIRE,
                                 __HIP_MEMORY_SCOPE_AGENT) < nch) { }
    }
    __syncthreads();
    // ---- phase 2: place edges (atomic-free; row_ptr via agent-scope loads) ----
    int stride = nch * 256;
    for (int e = bid * 256 + tid; e < E; e += stride) {
        int d = dst[e];
        int rp = __hip_atomic_load(&row_ptr[d], __ATOMIC_RELAXED,
                                   __HIP_MEMORY_SCOPE_AGENT);
        col[rp + pos[e]] = src[e];
    }
}

// ---------- lin0 (MFMA): y0[N,64](fp8) = bf16(x[N,128]) @ bf16(w0a) ----------
__global__ __launch_bounds__(256, 6) void k_lin0(
    const float4* __restrict__ x4, const float* __restrict__ w,
    u8* __restrict__ y, int N)
{
    __shared__ __align__(16) uint32 t32[16 * 68];
    int tid = threadIdx.x;
    int wid = tid >> 6, lane = tid & 63;
    int quad = lane >> 4, n15 = lane & 15;
    int mycol = wid * 16 + n15;
    bf16x8 fb[4];
    #pragma unroll
    for (int s = 0; s < 4; s++)
        #pragma unroll
        for (int j = 0; j < 8; j++)
            fb[s][j] = (short)f2bf(w[(s * 32 + quad * 8 + j) * HID + mycol]);
    int snode = tid >> 4, sk = tid & 15;
    for (long g0 = (long)blockIdx.x * 16; g0 < N; g0 += (long)gridDim.x * 16) {
        long node = g0 + snode;
        if (node < N) {
            float4 v0 = x4[node * 32 + sk * 2];
            float4 v1 = x4[node * 32 + sk * 2 + 1];
            uint32 p[4] = {pack2(v0.x, v0.y), pack2(v0.z, v0.w),
                           pack2(v1.x, v1.y), pack2(v1.z, v1.w)};
            *(uint4*)((char*)t32 + snode * 272 + sk * 16) = *(uint4*)p;
        }
        __syncthreads();
        f32x4 acc = {0.f, 0.f, 0.f, 0.f};
        #pragma unroll
        for (int s = 0; s < 4; s++) {
            bf16x8 a = *(const bf16x8*)((const char*)t32 + n15 * 272 + s * 64 + quad * 16);
            acc = __builtin_amdgcn_mfma_f32_16x16x32_bf16(a, fb[s], acc, 0, 0, 0);
        }
        #pragma unroll
        for (int r = 0; r < 4; r++) {
            long n = g0 + quad * 4 + r;
            if (n < N) y[n * HID + mycol] = f2fp8(acc[r]);
        }
        __syncthreads();
    }
}

// ---------- agg0f (MFMA): t=relu((1+e)y0+Σnbr+b0a); y1=relu(t@w0b+b0b)@w1a ----------
__global__ __launch_bounds__(256, 6) void k_agg0f(
    const uint32* __restrict__ y8, const int* __restrict__ row_ptr,
    const int* __restrict__ col, const float* __restrict__ epsp,
    const float* __restrict__ ba, const float* __restrict__ wb,
    const float* __restrict__ bb, const float* __restrict__ w1a,
    u8* __restrict__ y1, int N)
{
    __shared__ __align__(16) uint32 t32[16 * 36];
    __shared__ __align__(16) uint32 h32[16 * 36];
    int tid = threadIdx.x;
    int wid = tid >> 6, lane = tid & 63;
    int c2 = lane & 15, h = lane >> 4;
    int quad = lane >> 4, n15 = lane & 15;
    int n0 = wid * 4;
    int mycol = wid * 16 + n15;
    float e = 1.f + epsp[0];
    float4 bav = ((const float4*)ba)[c2];
    float bbv = bb[mycol];
    bf16x8 fb[2], f1[2];
    #pragma unroll
    for (int s = 0; s < 2; s++)
        #pragma unroll
        for (int j = 0; j < 8; j++) {
            fb[s][j] = (short)f2bf(wb[(s * 32 + quad * 8 + j) * HID + mycol]);
            f1[s][j] = (short)f2bf(w1a[(s * 32 + quad * 8 + j) * HID + mycol]);
        }
    for (long g0 = (long)blockIdx.x * 16; g0 < N; g0 += (long)gridDim.x * 16) {
        for (int m = 0; m < 4; m++) {
            long node = g0 + n0 + m;
            float a0 = 0.f, a1 = 0.f, a2 = 0.f, a3 = 0.f;
            if (node < N) {
                int rs = row_ptr[node], re = row_ptr[node + 1];
                gather_nbrs8(y8, col, rs, re, h, c2, a0, a1, a2, a3);
                if (h == 0) {
                    f32x2 lo = __builtin_amdgcn_cvt_pk_f32_fp8((int)y8[node * 16 + c2], false);
                    f32x2 hi = __builtin_amdgcn_cvt_pk_f32_fp8((int)y8[node * 16 + c2], true);
                    a0 = fmaf(e, lo.x, a0); a1 = fmaf(e, lo.y, a1);
                    a2 = fmaf(e, hi.x, a2); a3 = fmaf(e, hi.y, a3);
                }
            }
            a0 += __shfl_xor(a0, 16); a0 += __shfl_xor(a0, 32);
            a1 += __shfl_xor(a1, 16); a1 += __shfl_xor(a1, 32);
            a2 += __shfl_xor(a2, 16); a2 += __shfl_xor(a2, 32);
            a3 += __shfl_xor(a3, 16); a3 += __shfl_xor(a3, 32);
            if (h == 0) {
                t32[(n0 + m) * 36 + 2 * c2]     = pack2(fmaxf(a0 + bav.x, 0.f),
                                                        fmaxf(a1 + bav.y, 0.f));
                t32[(n0 + m) * 36 + 2 * c2 + 1] = pack2(fmaxf(a2 + bav.z, 0.f),
                                                        fmaxf(a3 + bav.w, 0.f));
            }
        }
        __syncthreads();
        f32x4 acc = {bbv, bbv, bbv, bbv};
        {
            bf16x8 a0 = *(const bf16x8*)((const char*)t32 + n15 * 144 + quad * 16);
            bf16x8 a1 = *(const bf16x8*)((const char*)t32 + n15 * 144 + 64 + quad * 16);
            acc = __builtin_amdgcn_mfma_f32_16x16x32_bf16(a0, fb[0], acc, 0, 0, 0);
            acc = __builtin_amdgcn_mfma_f32_16x16x32_bf16(a1, fb[1], acc, 0, 0, 0);
        }
        #pragma unroll
        for (int r = 0; r < 4; r++)
            ((short*)h32)[(quad * 4 + r) * 72 + mycol] = (short)f2bf(fmaxf(acc[r], 0.f));
        __syncthreads();
        f32x4 acc2 = {0.f, 0.f, 0.f, 0.f};
        {
            bf16x8 a0 = *(const bf16x8*)((const char*)h32 + n15 * 144 + quad * 16);
            bf16x8 a1 = *(const bf16x8*)((const char*)h32 + n15 * 144 + 64 + quad * 16);
            acc2 = __builtin_amdgcn_mfma_f32_16x16x32_bf16(a0, f1[0], acc2, 0, 0, 0);
            acc2 = __builtin_amdgcn_mfma_f32_16x16x32_bf16(a1, f1[1], acc2, 0, 0, 0);
        }
        #pragma unroll
        for (int r = 0; r < 4; r++) {
            long n = g0 + quad * 4 + r;
            if (n < N) y1[n * HID + mycol] = f2fp8(acc2[r]);
        }
    }
}

// ---------- agg1 (MFMA): gather + MLP-b + pooling ----------
__global__ __launch_bounds__(256, 6) void k_agg1(
    const uint32* __restrict__ y8, const int* __restrict__ row_ptr,
    const int* __restrict__ col, const float* __restrict__ epsp,
    const float* __restrict__ ba, const float* __restrict__ wb,
    const float* __restrict__ bb, const int* __restrict__ batch,
    float* __restrict__ pooled, int N)
{
    __shared__ __align__(16) uint32 t32[16 * 36];
    int tid = threadIdx.x;
    int wid = tid >> 6, lane = tid & 63;
    int c2 = lane & 15, h = lane >> 4;
    int quad = lane >> 4, n15 = lane & 15;
    int n0 = wid * 4;
    int mycol = wid * 16 + n15;
    float e = 1.f + epsp[0];
    float4 bav = ((const float4*)ba)[c2];
    float bbv = bb[mycol];
    bf16x8 fb[2];
    #pragma unroll
    for (int s = 0; s < 2; s++)
        #pragma unroll
        for (int j = 0; j < 8; j++)
            fb[s][j] = (short)f2bf(wb[(s * 32 + quad * 8 + j) * HID + mycol]);
    for (long g0 = (long)blockIdx.x * 16; g0 < N; g0 += (long)gridDim.x * 16) {
        for (int m = 0; m < 4; m++) {
            long node = g0 + n0 + m;
            float a0 = 0.f, a1 = 0.f, a2 = 0.f, a3 = 0.f;
            if (node < N) {
                int rs = row_ptr[node], re = row_ptr[node + 1];
                gather_nbrs8(y8, col, rs, re, h, c2, a0, a1, a2, a3);
                if (h == 0) {
                    f32x2 lo = __builtin_amdgcn_cvt_pk_f32_fp8((int)y8[node * 16 + c2], false);
                    f32x2 hi = __builtin_amdgcn_cvt_pk_f32_fp8((int)y8[node * 16 + c2], true);
                    a0 = fmaf(e, lo.x, a0); a1 = fmaf(e, lo.y, a1);
                    a2 = fmaf(e, hi.x, a2); a3 = fmaf(e, hi.y, a3);
                }
            }
            a0 += __shfl_xor(a0, 16); a0 += __shfl_xor(a0, 32);
            a1 += __shfl_xor(a1, 16); a1 += __shfl_xor(a1, 32);
            a2 += __shfl_xor(a2, 16); a2 += __shfl_xor(a2, 32);
            a3 += __shfl_xor(a3, 16); a3 += __shfl_xor(a3, 32);
            if (h == 0) {
                t32[(n0 + m) * 36 + 2 * c2]     = pack2(fmaxf(a0 + bav.x, 0.f),
                                                        fmaxf(a1 + bav.y, 0.f));
                t32[(n0 + m) * 36 + 2 * c2 + 1] = pack2(fmaxf(a2 + bav.z, 0.f),
                                                        fmaxf(a3 + bav.w, 0.f));
            }
        }
        __syncthreads();
        f32x4 acc = {bbv, bbv, bbv, bbv};
        {
            bf16x8 a0 = *(const bf16x8*)((const char*)t32 + n15 * 144 + quad * 16);
            bf16x8 a1 = *(const bf16x8*)((const char*)t32 + n15 * 144 + 64 + quad * 16);
            acc = __builtin_amdgcn_mfma_f32_16x16x32_bf16(a0, fb[0], acc, 0, 0, 0);
            acc = __builtin_amdgcn_mfma_f32_16x16x32_bf16(a1, fb[1], acc, 0, 0, 0);
        }
        float rv[4];
        #pragma unroll
        for (int r = 0; r < 4; r++) rv[r] = fmaxf(acc[r], 0.f);
        int nv = (int)((N - g0) < 16 ? (N - g0) : 16);
        int bf_ = batch[g0], bl_ = batch[g0 + nv - 1];
        if (bf_ == bl_) {
            float s = 0.f;
            #pragma unroll
            for (int r = 0; r < 4; r++)
                if (quad * 4 + r < nv) s += rv[r];
            s += __shfl_xor(s, 16);
            s += __shfl_xor(s, 32);
            if (quad == 0)
                atomicAdd(&pooled[(long)bf_ * HID + mycol], s);
        } else {
            #pragma unroll
            for (int r = 0; r < 4; r++) {
                long n = g0 + quad * 4 + r;
                if (n < N)
                    atomicAdd(&pooled[(long)batch[n] * HID + mycol], rv[r]);
            }
        }
        __syncthreads();
    }
}

// ---------- head ----------
__global__ __launch_bounds__(64) void k_head(
    const float* __restrict__ pooled, const float* __restrict__ fcw,
    const float* __restrict__ fcb, float* __restrict__ out)
{
    int g = blockIdx.x;
    int l = threadIdx.x;
    float logit = -INFINITY;
    if (l < OUT_CH) {
        float acc = fcb[l];
        #pragma unroll
        for (int k = 0; k < HID; k++)
            acc = fmaf(pooled[g * HID + k], fcw[k * OUT_CH + l], acc);
        logit = acc;
    }
    float m = logit;
    #pragma unroll
    for (int off = 32; off; off >>= 1) m = fmaxf(m, __shfl_xor(m, off));
    float ex = (l < OUT_CH) ? expf(logit - m) : 0.0f;
    float s = ex;
    #pragma unroll
    for (int off = 32; off; off >>= 1) s += __shfl_xor(s, off);
    if (l < OUT_CH) out[g * OUT_CH + l] = logit - m - logf(s);
}

extern "C" void kernel_launch(void* const* d_in, const int* in_sizes, int n_in,
                              void* d_out, int out_size, void* d_ws, size_t ws_size,
                              hipStream_t stream) {
    const float* x    = (const float*)d_in[0];
    const int*   ei   = (const int*)d_in[1];
    const int*   batch= (const int*)d_in[2];
    const float* eps0 = (const float*)d_in[3];
    const float* w0a  = (const float*)d_in[4];
    const float* b0a  = (const float*)d_in[5];
    const float* w0b  = (const float*)d_in[6];
    const float* b0b  = (const float*)d_in[7];
    const float* eps1 = (const float*)d_in[8];
    const float* w1a  = (const float*)d_in[9];
    const float* b1a  = (const float*)d_in[10];
    const float* w1b  = (const float*)d_in[11];
    const float* b1b  = (const float*)d_in[12];
    const float* fcw  = (const float*)d_in[13];
    const float* fcb  = (const float*)d_in[14];
    float* out = (float*)d_out;

    const int N = in_sizes[0] / IN_CH;       // 50000
    const int E = in_sizes[1] / 2;           // 800000
    const int G = out_size / OUT_CH;         // 512
    const int* src = ei;
    const int* dst = ei + E;

    // workspace layout (bytes):
    // [0, 200064)            row_ptr  (N+1 ints)
    // [200064, 3400064)      col      (E ints)
    // [3400064, 6600064)     y0       (N*64 fp8)
    // [6600064, 9800064)     y1       (N*64 fp8)
    // [9800064, 10000064)    cnt      (N ints)
    // [10000064, 10000068)   counter
    // [10000068, 10000072)   counter2
    // [10000128, 10000384)   partials (49 ints, padded)
    // [10000384, 10131456)   pooled   (G*64 fp32)
    // [10131456, 13331456)   pos      (E ints)
    char* ws = (char*)d_ws;
    int*    row_ptr  = (int*)(ws);
    int*    colv     = (int*)(ws + 200064);
    u8*     y0       = (u8*)(ws + 3400064);
    u8*     y1       = (u8*)(ws + 6600064);
    int*    cnt      = (int*)(ws + 9800064);
    int*    counter  = (int*)(ws + 10000064);
    int*    counter2 = (int*)(ws + 10000068);
    int*    partials = (int*)(ws + 10000128);
    float*  pooled   = (float*)(ws + 10000384);
    int*    pos      = (int*)(ws + 10131456);

    // one memset covers cnt + counters + partials + pooled
    hipMemsetAsync(cnt, 0, 331392, stream);

    int eb = (E + 255) / 256;                   // 3125
    int nb = (N + 31) / 32;                     // 1563
    int nch = (N + 1023) / 1024;                // 49 blocks, all co-resident
    k_count<<<eb, 256, 0, stream>>>(dst, cnt, pos, E);
    k_scanplace<<<nch, 256, 0, stream>>>(cnt, row_ptr, partials, counter, counter2,
                                         src, dst, pos, colv, N, E, nch);
    k_lin0<<<nb, 256, 0, stream>>>((const float4*)x, w0a, y0, N);
    k_agg0f<<<nb, 256, 0, stream>>>((const uint32*)y0, row_ptr, colv, eps0,
                                    b0a, w0b, b0b, w1a, y1, N);
    k_agg1<<<nb, 256, 0, stream>>>((const uint32*)y1, row_ptr, colv, eps1,
                                   b1a, w1b, b1b, batch, pooled, N);
    k_head<<<G, 64, 0, stream>>>(pooled, fcw, fcb, out);
}

// Round 16
// 216.540 us; speedup vs baseline: 1.1817x; 1.1817x over previous
//
#include <hip/hip_runtime.h>
#include <math.h>

#define IN_CH 128
#define HID 64
#define OUT_CH 10

typedef unsigned int uint32;
typedef unsigned char u8;
typedef unsigned short bf16u;
typedef __attribute__((ext_vector_type(8))) short bf16x8;
typedef __attribute__((ext_vector_type(4))) float f32x4;
typedef __attribute__((ext_vector_type(2))) float f32x2;

static __device__ inline bf16u f2bf(float f) {
    uint32 u = __float_as_uint(f);
    u += 0x7fff + ((u >> 16) & 1);          // round-nearest-even
    return (bf16u)(u >> 16);
}
static __device__ inline uint32 pack2(float a, float b) {
    return (uint32)f2bf(a) | ((uint32)f2bf(b) << 16);
}
static __device__ inline u8 f2fp8(float v) {
    uint32 p = __builtin_amdgcn_cvt_pk_fp8_f32(v, v, 0, false);
    return (u8)(p & 0xff);
}
static __device__ inline void acc_fp8x4(uint32 u, float& a0, float& a1,
                                        float& a2, float& a3) {
    f32x2 lo = __builtin_amdgcn_cvt_pk_f32_fp8((int)u, false);
    f32x2 hi = __builtin_amdgcn_cvt_pk_f32_fp8((int)u, true);
    a0 += lo.x; a1 += lo.y; a2 += hi.x; a3 += hi.y;
}

// neighbor-sum, fp8 y rows (16 dwords). lanes: c2=lane&15 (4 ch), h=lane>>4
static __device__ inline void gather_nbrs8(
    const uint32* __restrict__ y8, const int* __restrict__ col,
    int rs, int re, int h, int c2,
    float& a0, float& a1, float& a2, float& a3)
{
    int j = rs;
    for (; j + 16 <= re; j += 16) {
        int s0 = col[j + h];
        int s1 = col[j + 4 + h];
        int s2 = col[j + 8 + h];
        int s3 = col[j + 12 + h];
        uint32 u0 = y8[(long)s0 * 16 + c2];
        uint32 u1 = y8[(long)s1 * 16 + c2];
        uint32 u2 = y8[(long)s2 * 16 + c2];
        uint32 u3 = y8[(long)s3 * 16 + c2];
        acc_fp8x4(u0, a0, a1, a2, a3);
        acc_fp8x4(u1, a0, a1, a2, a3);
        acc_fp8x4(u2, a0, a1, a2, a3);
        acc_fp8x4(u3, a0, a1, a2, a3);
    }
    for (; j + 4 <= re; j += 4) {
        uint32 u = y8[(long)col[j + h] * 16 + c2];
        acc_fp8x4(u, a0, a1, a2, a3);
    }
    int r = re - j;
    if (h < r) {
        uint32 u = y8[(long)col[j + h] * 16 + c2];
        acc_fp8x4(u, a0, a1, a2, a3);
    }
}

// ---------- CSR build: degree count + per-edge ordinal ----------
__global__ __launch_bounds__(256) void k_count(
    const int* __restrict__ dst, int* __restrict__ cnt,
    int* __restrict__ pos, int E)
{
    int e = blockIdx.x * 256 + threadIdx.x;
    if (e < E) pos[e] = atomicAdd(&cnt[dst[e]], 1);
}

// ---------- single-kernel scan: cnt[N] -> row_ptr[N+1] (49 co-resident blocks) ----
__global__ __launch_bounds__(256) void k_scan(
    const int* __restrict__ cnt, int* __restrict__ row_ptr,
    int* __restrict__ partials, int* __restrict__ counter, int N, int E, int nch)
{
    __shared__ int red[256];
    int tid = threadIdx.x;
    int bid = blockIdx.x;
    long base = (long)bid * 1024 + tid * 4;
    int v[4]; int s = 0;
    #pragma unroll
    for (int i = 0; i < 4; i++) {
        long idx = base + i;
        v[i] = (idx < N) ? cnt[idx] : 0;
        s += v[i];
    }
    red[tid] = s;
    __syncthreads();
    for (int off = 1; off < 256; off <<= 1) {
        int t = (tid >= off) ? red[tid - off] : 0;
        __syncthreads();
        red[tid] += t;
        __syncthreads();
    }
    int myexcl = red[tid] - s;
    if (tid == 255) {
        __hip_atomic_store(&partials[bid], red[255], __ATOMIC_RELEASE,
                           __HIP_MEMORY_SCOPE_AGENT);
        atomicAdd(counter, 1);
    }
    if (tid == 0) {
        while (__hip_atomic_load(counter, __ATOMIC_ACQUIRE,
                                 __HIP_MEMORY_SCOPE_AGENT) < nch) { }
    }
    __syncthreads();
    int off = 0;
    for (int i = tid; i < bid; i += 256)
        off += __hip_atomic_load(&partials[i], __ATOMIC_RELAXED,
                                 __HIP_MEMORY_SCOPE_AGENT);
    __syncthreads();
    red[tid] = off;
    __syncthreads();
    for (int o = 128; o; o >>= 1) {
        if (tid < o) red[tid] += red[tid + o];
        __syncthreads();
    }
    int run = red[0] + myexcl;
    #pragma unroll
    for (int i = 0; i < 4; i++) {
        long idx = base + i;
        if (idx < N) row_ptr[idx] = run;
        run += v[i];
    }
    if (bid == 0 && tid == 0) row_ptr[N] = E;
}

// ---------- CSR place: atomic-free, full grid width ----------
__global__ __launch_bounds__(256) void k_place(
    const int* __restrict__ src, const int* __restrict__ dst,
    const int* __restrict__ row_ptr, const int* __restrict__ pos,
    int* __restrict__ col, int E)
{
    int e = blockIdx.x * 256 + threadIdx.x;
    if (e >= E) return;
    col[row_ptr[dst[e]] + pos[e]] = src[e];
}

// ---------- lin0 (MFMA): y0[N,64](fp8) = bf16(x[N,128]) @ bf16(w0a) ----------
__global__ __launch_bounds__(256, 6) void k_lin0(
    const float4* __restrict__ x4, const float* __restrict__ w,
    u8* __restrict__ y, int N)
{
    __shared__ __align__(16) uint32 t32[16 * 68];
    int tid = threadIdx.x;
    int wid = tid >> 6, lane = tid & 63;
    int quad = lane >> 4, n15 = lane & 15;
    int mycol = wid * 16 + n15;
    bf16x8 fb[4];
    #pragma unroll
    for (int s = 0; s < 4; s++)
        #pragma unroll
        for (int j = 0; j < 8; j++)
            fb[s][j] = (short)f2bf(w[(s * 32 + quad * 8 + j) * HID + mycol]);
    int snode = tid >> 4, sk = tid & 15;
    for (long g0 = (long)blockIdx.x * 16; g0 < N; g0 += (long)gridDim.x * 16) {
        long node = g0 + snode;
        if (node < N) {
            float4 v0 = x4[node * 32 + sk * 2];
            float4 v1 = x4[node * 32 + sk * 2 + 1];
            uint32 p[4] = {pack2(v0.x, v0.y), pack2(v0.z, v0.w),
                           pack2(v1.x, v1.y), pack2(v1.z, v1.w)};
            *(uint4*)((char*)t32 + snode * 272 + sk * 16) = *(uint4*)p;
        }
        __syncthreads();
        f32x4 acc = {0.f, 0.f, 0.f, 0.f};
        #pragma unroll
        for (int s = 0; s < 4; s++) {
            bf16x8 a = *(const bf16x8*)((const char*)t32 + n15 * 272 + s * 64 + quad * 16);
            acc = __builtin_amdgcn_mfma_f32_16x16x32_bf16(a, fb[s], acc, 0, 0, 0);
        }
        #pragma unroll
        for (int r = 0; r < 4; r++) {
            long n = g0 + quad * 4 + r;
            if (n < N) y[n * HID + mycol] = f2fp8(acc[r]);
        }
        __syncthreads();
    }
}

// ---------- agg0f (MFMA): t=relu((1+e)y0+Σnbr+b0a); y1=relu(t@w0b+b0b)@w1a ----------
__global__ __launch_bounds__(256, 6) void k_agg0f(
    const uint32* __restrict__ y8, const int* __restrict__ row_ptr,
    const int* __restrict__ col, const float* __restrict__ epsp,
    const float* __restrict__ ba, const float* __restrict__ wb,
    const float* __restrict__ bb, const float* __restrict__ w1a,
    u8* __restrict__ y1, int N)
{
    __shared__ __align__(16) uint32 t32[16 * 36];
    __shared__ __align__(16) uint32 h32[16 * 36];
    int tid = threadIdx.x;
    int wid = tid >> 6, lane = tid & 63;
    int c2 = lane & 15, h = lane >> 4;
    int quad = lane >> 4, n15 = lane & 15;
    int n0 = wid * 4;
    int mycol = wid * 16 + n15;
    float e = 1.f + epsp[0];
    float4 bav = ((const float4*)ba)[c2];
    float bbv = bb[mycol];
    bf16x8 fb[2], f1[2];
    #pragma unroll
    for (int s = 0; s < 2; s++)
        #pragma unroll
        for (int j = 0; j < 8; j++) {
            fb[s][j] = (short)f2bf(wb[(s * 32 + quad * 8 + j) * HID + mycol]);
            f1[s][j] = (short)f2bf(w1a[(s * 32 + quad * 8 + j) * HID + mycol]);
        }
    for (long g0 = (long)blockIdx.x * 16; g0 < N; g0 += (long)gridDim.x * 16) {
        for (int m = 0; m < 4; m++) {
            long node = g0 + n0 + m;
            float a0 = 0.f, a1 = 0.f, a2 = 0.f, a3 = 0.f;
            if (node < N) {
                int rs = row_ptr[node], re = row_ptr[node + 1];
                gather_nbrs8(y8, col, rs, re, h, c2, a0, a1, a2, a3);
                if (h == 0) {
                    f32x2 lo = __builtin_amdgcn_cvt_pk_f32_fp8((int)y8[node * 16 + c2], false);
                    f32x2 hi = __builtin_amdgcn_cvt_pk_f32_fp8((int)y8[node * 16 + c2], true);
                    a0 = fmaf(e, lo.x, a0); a1 = fmaf(e, lo.y, a1);
                    a2 = fmaf(e, hi.x, a2); a3 = fmaf(e, hi.y, a3);
                }
            }
            a0 += __shfl_xor(a0, 16); a0 += __shfl_xor(a0, 32);
            a1 += __shfl_xor(a1, 16); a1 += __shfl_xor(a1, 32);
            a2 += __shfl_xor(a2, 16); a2 += __shfl_xor(a2, 32);
            a3 += __shfl_xor(a3, 16); a3 += __shfl_xor(a3, 32);
            if (h == 0) {
                t32[(n0 + m) * 36 + 2 * c2]     = pack2(fmaxf(a0 + bav.x, 0.f),
                                                        fmaxf(a1 + bav.y, 0.f));
                t32[(n0 + m) * 36 + 2 * c2 + 1] = pack2(fmaxf(a2 + bav.z, 0.f),
                                                        fmaxf(a3 + bav.w, 0.f));
            }
        }
        __syncthreads();
        f32x4 acc = {bbv, bbv, bbv, bbv};
        {
            bf16x8 a0 = *(const bf16x8*)((const char*)t32 + n15 * 144 + quad * 16);
            bf16x8 a1 = *(const bf16x8*)((const char*)t32 + n15 * 144 + 64 + quad * 16);
            acc = __builtin_amdgcn_mfma_f32_16x16x32_bf16(a0, fb[0], acc, 0, 0, 0);
            acc = __builtin_amdgcn_mfma_f32_16x16x32_bf16(a1, fb[1], acc, 0, 0, 0);
        }
        #pragma unroll
        for (int r = 0; r < 4; r++)
            ((short*)h32)[(quad * 4 + r) * 72 + mycol] = (short)f2bf(fmaxf(acc[r], 0.f));
        __syncthreads();
        f32x4 acc2 = {0.f, 0.f, 0.f, 0.f};
        {
            bf16x8 a0 = *(const bf16x8*)((const char*)h32 + n15 * 144 + quad * 16);
            bf16x8 a1 = *(const bf16x8*)((const char*)h32 + n15 * 144 + 64 + quad * 16);
            acc2 = __builtin_amdgcn_mfma_f32_16x16x32_bf16(a0, f1[0], acc2, 0, 0, 0);
            acc2 = __builtin_amdgcn_mfma_f32_16x16x32_bf16(a1, f1[1], acc2, 0, 0, 0);
        }
        #pragma unroll
        for (int r = 0; r < 4; r++) {
            long n = g0 + quad * 4 + r;
            if (n < N) y1[n * HID + mycol] = f2fp8(acc2[r]);
        }
    }
}

// ---------- agg1 (MFMA): gather + MLP-b + pooling ----------
__global__ __launch_bounds__(256, 6) void k_agg1(
    const uint32* __restrict__ y8, const int* __restrict__ row_ptr,
    const int* __restrict__ col, const float* __restrict__ epsp,
    const float* __restrict__ ba, const float* __restrict__ wb,
    const float* __restrict__ bb, const int* __restrict__ batch,
    float* __restrict__ pooled, int N)
{
    __shared__ __align__(16) uint32 t32[16 * 36];
    int tid = threadIdx.x;
    int wid = tid >> 6, lane = tid & 63;
    int c2 = lane & 15, h = lane >> 4;
    int quad = lane >> 4, n15 = lane & 15;
    int n0 = wid * 4;
    int mycol = wid * 16 + n15;
    float e = 1.f + epsp[0];
    float4 bav = ((const float4*)ba)[c2];
    float bbv = bb[mycol];
    bf16x8 fb[2];
    #pragma unroll
    for (int s = 0; s < 2; s++)
        #pragma unroll
        for (int j = 0; j < 8; j++)
            fb[s][j] = (short)f2bf(wb[(s * 32 + quad * 8 + j) * HID + mycol]);
    for (long g0 = (long)blockIdx.x * 16; g0 < N; g0 += (long)gridDim.x * 16) {
        for (int m = 0; m < 4; m++) {
            long node = g0 + n0 + m;
            float a0 = 0.f, a1 = 0.f, a2 = 0.f, a3 = 0.f;
            if (node < N) {
                int rs = row_ptr[node], re = row_ptr[node + 1];
                gather_nbrs8(y8, col, rs, re, h, c2, a0, a1, a2, a3);
                if (h == 0) {
                    f32x2 lo = __builtin_amdgcn_cvt_pk_f32_fp8((int)y8[node * 16 + c2], false);
                    f32x2 hi = __builtin_amdgcn_cvt_pk_f32_fp8((int)y8[node * 16 + c2], true);
                    a0 = fmaf(e, lo.x, a0); a1 = fmaf(e, lo.y, a1);
                    a2 = fmaf(e, hi.x, a2); a3 = fmaf(e, hi.y, a3);
                }
            }
            a0 += __shfl_xor(a0, 16); a0 += __shfl_xor(a0, 32);
            a1 += __shfl_xor(a1, 16); a1 += __shfl_xor(a1, 32);
            a2 += __shfl_xor(a2, 16); a2 += __shfl_xor(a2, 32);
            a3 += __shfl_xor(a3, 16); a3 += __shfl_xor(a3, 32);
            if (h == 0) {
                t32[(n0 + m) * 36 + 2 * c2]     = pack2(fmaxf(a0 + bav.x, 0.f),
                                                        fmaxf(a1 + bav.y, 0.f));
                t32[(n0 + m) * 36 + 2 * c2 + 1] = pack2(fmaxf(a2 + bav.z, 0.f),
                                                        fmaxf(a3 + bav.w, 0.f));
            }
        }
        __syncthreads();
        f32x4 acc = {bbv, bbv, bbv, bbv};
        {
            bf16x8 a0 = *(const bf16x8*)((const char*)t32 + n15 * 144 + quad * 16);
            bf16x8 a1 = *(const bf16x8*)((const char*)t32 + n15 * 144 + 64 + quad * 16);
            acc = __builtin_amdgcn_mfma_f32_16x16x32_bf16(a0, fb[0], acc, 0, 0, 0);
            acc = __builtin_amdgcn_mfma_f32_16x16x32_bf16(a1, fb[1], acc, 0, 0, 0);
        }
        float rv[4];
        #pragma unroll
        for (int r = 0; r < 4; r++) rv[r] = fmaxf(acc[r], 0.f);
        int nv = (int)((N - g0) < 16 ? (N - g0) : 16);
        int bf_ = batch[g0], bl_ = batch[g0 + nv - 1];
        if (bf_ == bl_) {
            float s = 0.f;
            #pragma unroll
            for (int r = 0; r < 4; r++)
                if (quad * 4 + r < nv) s += rv[r];
            s += __shfl_xor(s, 16);
            s += __shfl_xor(s, 32);
            if (quad == 0)
                atomicAdd(&pooled[(long)bf_ * HID + mycol], s);
        } else {
            #pragma unroll
            for (int r = 0; r < 4; r++) {
                long n = g0 + quad * 4 + r;
                if (n < N)
                    atomicAdd(&pooled[(long)batch[n] * HID + mycol], rv[r]);
            }
        }
        __syncthreads();
    }
}

// ---------- head ----------
__global__ __launch_bounds__(64) void k_head(
    const float* __restrict__ pooled, const float* __restrict__ fcw,
    const float* __restrict__ fcb, float* __restrict__ out)
{
    int g = blockIdx.x;
    int l = threadIdx.x;
    float logit = -INFINITY;
    if (l < OUT_CH) {
        float acc = fcb[l];
        #pragma unroll
        for (int k = 0; k < HID; k++)
            acc = fmaf(pooled[g * HID + k], fcw[k * OUT_CH + l], acc);
        logit = acc;
    }
    float m = logit;
    #pragma unroll
    for (int off = 32; off; off >>= 1) m = fmaxf(m, __shfl_xor(m, off));
    float ex = (l < OUT_CH) ? expf(logit - m) : 0.0f;
    float s = ex;
    #pragma unroll
    for (int off = 32; off; off >>= 1) s += __shfl_xor(s, off);
    if (l < OUT_CH) out[g * OUT_CH + l] = logit - m - logf(s);
}

extern "C" void kernel_launch(void* const* d_in, const int* in_sizes, int n_in,
                              void* d_out, int out_size, void* d_ws, size_t ws_size,
                              hipStream_t stream) {
    const float* x    = (const float*)d_in[0];
    const int*   ei   = (const int*)d_in[1];
    const int*   batch= (const int*)d_in[2];
    const float* eps0 = (const float*)d_in[3];
    const float* w0a  = (const float*)d_in[4];
    const float* b0a  = (const float*)d_in[5];
    const float* w0b  = (const float*)d_in[6];
    const float* b0b  = (const float*)d_in[7];
    const float* eps1 = (const float*)d_in[8];
    const float* w1a  = (const float*)d_in[9];
    const float* b1a  = (const float*)d_in[10];
    const float* w1b  = (const float*)d_in[11];
    const float* b1b  = (const float*)d_in[12];
    const float* fcw  = (const float*)d_in[13];
    const float* fcb  = (const float*)d_in[14];
    float* out = (float*)d_out;

    const int N = in_sizes[0] / IN_CH;       // 50000
    const int E = in_sizes[1] / 2;           // 800000
    const int G = out_size / OUT_CH;         // 512
    const int* src = ei;
    const int* dst = ei + E;

    // workspace layout (bytes):
    // [0, 200064)            row_ptr  (N+1 ints)
    // [200064, 3400064)      col      (E ints)
    // [3400064, 6600064)     y0       (N*64 fp8)
    // [6600064, 9800064)     y1       (N*64 fp8)
    // [9800064, 10000064)    cnt      (N ints)
    // [10000064, 10000068)   counter
    // [10000128, 10000384)   partials (49 ints, padded)
    // [10000384, 10131456)   pooled   (G*64 fp32)
    // [10131456, 13331456)   pos      (E ints)
    char* ws = (char*)d_ws;
    int*    row_ptr  = (int*)(ws);
    int*    colv     = (int*)(ws + 200064);
    u8*     y0       = (u8*)(ws + 3400064);
    u8*     y1       = (u8*)(ws + 6600064);
    int*    cnt      = (int*)(ws + 9800064);
    int*    counter  = (int*)(ws + 10000064);
    int*    partials = (int*)(ws + 10000128);
    float*  pooled   = (float*)(ws + 10000384);
    int*    pos      = (int*)(ws + 10131456);

    // one memset covers cnt + counter + partials + pooled
    hipMemsetAsync(cnt, 0, 331392, stream);

    int eb = (E + 255) / 256;                   // 3125
    int nb = (N + 31) / 32;                     // 1563
    int nch = (N + 1023) / 1024;                // 49 blocks, all co-resident
    k_count<<<eb, 256, 0, stream>>>(dst, cnt, pos, E);
    k_scan<<<nch, 256, 0, stream>>>(cnt, row_ptr, partials, counter, N, E, nch);
    k_place<<<eb, 256, 0, stream>>>(src, dst, row_ptr, pos, colv, E);

    k_lin0<<<nb, 256, 0, stream>>>((const float4*)x, w0a, y0, N);
    k_agg0f<<<nb, 256, 0, stream>>>((const uint32*)y0, row_ptr, colv, eps0,
                                    b0a, w0b, b0b, w1a, y1, N);
    k_agg1<<<nb, 256, 0, stream>>>((const uint32*)y1, row_ptr, colv, eps1,
                                   b1a, w1b, b1b, batch, pooled, N);
    k_head<<<G, 64, 0, stream>>>(pooled, fcw, fcb, out);
}